// Round 3
// baseline (284.955 us; speedup 1.0000x reference)
//
#include <hip/hip_runtime.h>

#define BCNT 16
#define TT 1024
#define DIN 384
#define H1 1024
#define H2 1024
#define KW 9

typedef __attribute__((ext_vector_type(8))) short bhalf8;   // 8 bf16 in 4 VGPRs
typedef __attribute__((ext_vector_type(4))) float f32x4;

typedef const __attribute__((address_space(1))) void* gas_ptr;
typedef __attribute__((address_space(3))) void* lds_ptr;

__device__ __forceinline__ float bf2f(unsigned short u) {
    return __uint_as_float(((unsigned int)u) << 16);
}
__device__ __forceinline__ unsigned short f2bf(float f) {
    unsigned int u = __float_as_uint(f);
    unsigned int r = (u + 0x7FFFu + ((u >> 16) & 1u)) >> 16;  // RNE
    return (unsigned short)r;
}
// mish(x) = x*tanh(log1p(e^x)) = x*(u^2+2u)/(u^2+2u+2), u=e^x (exact algebra)
__device__ __forceinline__ float mish_f(float x) {
    if (x > 20.f) return x;
    float u = __expf(x);
    float n = u * u + 2.f * u;
    return x * n / (n + 2.f);
}

// ---------------- prep kernels ----------------

// fused f32->bf16 cvt for input, w1_w, w2_w + zero sumsq (one launch)
__global__ __launch_bounds__(256) void k_cvt3z(
    const float* __restrict__ s0, unsigned short* __restrict__ d0, int n0,
    const float* __restrict__ s1, unsigned short* __restrict__ d1, int n1,
    const float* __restrict__ s2, unsigned short* __restrict__ d2, int n2,
    float* __restrict__ zb, int n3) {
    int i = blockIdx.x * 256 + threadIdx.x;
    const float* s; unsigned short* d; int j = i;
    if (i < n0) { s = s0; d = d0; }
    else if ((j = i - n0) < n1) { s = s1; d = d1; }
    else if ((j = i - n0 - n1) < n2) { s = s2; d = d2; }
    else if ((j = i - n0 - n1 - n2) < n3) {
        ((float4*)zb)[j] = make_float4(0.f, 0.f, 0.f, 0.f);
        return;
    } else return;
    float4 v = ((const float4*)s)[j];
    ushort4 o;
    o.x = f2bf(v.x); o.y = f2bf(v.y); o.z = f2bf(v.z); o.w = f2bf(v.w);
    ((ushort4*)d)[j] = o;
}

// per-(b,k): norm of d_w over c, then write dwn_s[b,c,k] = d_w/n * d_g * T
__global__ void k_norm_dwn(const float* __restrict__ d_w, const float* __restrict__ d_g,
                           float* __restrict__ dwn_s) {
    int idx = blockIdx.x;           // b*KW + k
    int b = idx / KW, k = idx % KW;
    float s = 0.f;
    for (int c = threadIdx.x; c < H1; c += 256) {
        float v = d_w[((size_t)b * H1 + c) * KW + k];
        s += v * v;
    }
    __shared__ float red[256];
    __shared__ float nsh;
    red[threadIdx.x] = s; __syncthreads();
    for (int st = 128; st > 0; st >>= 1) {
        if (threadIdx.x < st) red[threadIdx.x] += red[threadIdx.x + st];
        __syncthreads();
    }
    if (threadIdx.x == 0) nsh = fmaxf(sqrtf(red[0]), 1e-12f);
    __syncthreads();
    float n = nsh;
    for (int c = threadIdx.x; c < H1; c += 256) {
        size_t o = ((size_t)b * H1 + c) * KW + k;
        dwn_s[o] = d_w[o] / n * d_g[b * H1 + c] * (float)TT;
    }
}

// transpose+scale p_w AND accumulate per-(b,o) sum of squares
__global__ __launch_bounds__(256) void k_tpw2(const float* __restrict__ p_w,
                                              const float* __restrict__ p_g,
                                              unsigned short* __restrict__ pwTu,
                                              float* __restrict__ sumsq) {
    __shared__ float tile[32][33];
    __shared__ float red[8][32];
    int tx = threadIdx.x & 31, ty = threadIdx.x >> 5;  // 32 x 8
    int c0 = blockIdx.x * 32, o0 = blockIdx.y * 32, b = blockIdx.z;
    float s = 0.f;
#pragma unroll
    for (int j = 0; j < 4; j++) {
        float v = p_w[((size_t)b * H1 + c0 + ty + j * 8) * H2 + o0 + tx];
        tile[ty + j * 8][tx] = v;
        s += v * v;
    }
    red[ty][tx] = s;
    __syncthreads();
    if (ty == 0) {
        float t = 0.f;
#pragma unroll
        for (int r = 0; r < 8; r++) t += red[r][tx];
        atomicAdd(&sumsq[(size_t)b * H2 + o0 + tx], t);
    }
#pragma unroll
    for (int j = 0; j < 4; j++) {
        int o = o0 + ty + j * 8, c = c0 + tx;
        float v = tile[tx][ty + j * 8] * p_g[(size_t)b * H1 + c];
        pwTu[((size_t)b * H2 + o) * H1 + c] = f2bf(v);
    }
}

// depthwise conv along T, sliding window; 2 channels per thread (ushort2)
__global__ __launch_bounds__(256) void k_conv(const unsigned short* __restrict__ h,
                                              const float* __restrict__ dwn_s,
                                              const float* __restrict__ d_b,
                                              unsigned short* __restrict__ y) {
    int tid = threadIdx.x;
    int c2 = blockIdx.y * 256 + tid;
    int c = c2 * 2;
    int t0 = blockIdx.x * 64;
    int b = blockIdx.z;
    const ushort2* hb = (const ushort2*)(h + (size_t)b * TT * H1);
    ushort2* yb = (ushort2*)(y + (size_t)b * TT * H1);
    float k0[KW], k1[KW];
#pragma unroll
    for (int i = 0; i < KW; i++) {
        k0[i] = dwn_s[((size_t)b * H1 + c) * KW + i];
        k1[i] = dwn_s[((size_t)b * H1 + c + 1) * KW + i];
    }
    float db0 = d_b[b * H1 + c], db1 = d_b[b * H1 + c + 1];
    float w0[KW], w1[KW];
#pragma unroll
    for (int i = 0; i < 8; i++) {
        int t = t0 - 4 + i;
        if (t >= 0 && t < TT) {
            ushort2 v = hb[(size_t)t * (H1 / 2) + c2];
            w0[i] = bf2f(v.x); w1[i] = bf2f(v.y);
        } else { w0[i] = 0.f; w1[i] = 0.f; }
    }
    for (int j = 0; j < 64; j++) {
        int t = t0 + j;
        int tl = t + 4;
        if (tl < TT) {
            ushort2 v = hb[(size_t)tl * (H1 / 2) + c2];
            w0[8] = bf2f(v.x); w1[8] = bf2f(v.y);
        } else { w0[8] = 0.f; w1[8] = 0.f; }
        float a0 = db0, a1 = db1;
#pragma unroll
        for (int i = 0; i < KW; i++) { a0 += k0[i] * w0[i]; a1 += k1[i] * w1[i]; }
        ushort2 o; o.x = f2bf(a0); o.y = f2bf(a1);
        yb[(size_t)t * (H1 / 2) + c2] = o;
#pragma unroll
        for (int i = 0; i < 8; i++) { w0[i] = w0[i + 1]; w1[i] = w1[i + 1]; }
    }
}

// ------- gemm256: 256x256 tile, BK=32, ring-4 LDS, 512 thr, prefetch-3 -------
// C[m,n] = sum_k A[m,k]*B[n,k], bf16 K-contiguous. 8 waves as 2(M) x 4(N);
// wave output 128x64; acc[8][4] f32x4. nkt = K/32 tiles; tile kt lives in LDS
// slot kt&3 (ring of 4: A 16KB + B 16KB per slot = 128KB total).
// Safety (provable, not timing-based):
//  - STAGE(kt+3) issued at top of iter kt, AFTER the closing barrier of kt-1 ->
//    its slot's last reader already finished (issue-after-last-use; LDS write
//    cannot land before issue).
//  - vmcnt(12) = 3 tiles x 4 loads keeps 3 tiles in flight, guarantees tile kt
//    landed (per-wave) before the entry barrier; barrier makes it collective.
//  - 12 ds_read_b128 issued up-front, waited with counted lgkmcnt(6/4/2/0);
//    sched_barrier(0) pins issue-group order and stops MFMA hoisting (rule #18).
// Swizzle: LDS[r][slot s] = global[r][s ^ ((r>>1)&3)] (s = 16B granule, row=64B).
// Read side XORs identically; per-16-lane bank pattern = 8 banks 2-way (free).
// K order = sequential 32-chunks -> numerics identical to previous version.
// MODE 0: C=bf16(mish(v+bias[n]));  MODE 1: C=bf16(v*rsqrt(sumsq)+bias) batched.
// GS 0: 256 blocks, XCD gets 8 M-tiles x 4 N.  GS 1: batched, XCD gets 2 batches.
template <int MODE, int GS>
__global__ __launch_bounds__(512, 2) void gemm256(
    const unsigned short* __restrict__ A, const unsigned short* __restrict__ Bm,
    unsigned short* __restrict__ Cp, int Kdim, int lda, int ldb, int ldc,
    long sA, long sB, long sC,
    const float* __restrict__ bias, int biasStride,
    const float* __restrict__ sumsq) {
    __shared__ __attribute__((aligned(16))) unsigned short Asl[4][256 * 32];
    __shared__ __attribute__((aligned(16))) unsigned short Bsl[4][256 * 32];

    const int tid = threadIdx.x;
    const int lane = tid & 63, wv = tid >> 6;       // 8 waves
    const int wr = wv >> 2, wc = wv & 3;            // 2 x 4 wave grid

    int bx, by, bz;
    {
        int l = blockIdx.x;
        int xcd = l & 7, s = l >> 3;                // 256 blocks -> s: 0..31
        if constexpr (GS == 0) { bz = 0; bx = xcd * 8 + (s & 7); by = s >> 3; }
        else { bz = xcd * 2 + (s >> 4); int u = s & 15; bx = u & 3; by = u >> 2; }
    }
    const int bm = bx * 256, bn = by * 256;
    const unsigned short* Ab = A + (size_t)sA * bz;
    const unsigned short* Bb = Bm + (size_t)sB * bz;

    // staging map: one load = 64 lanes x 16B = 16 rows x 4 granules (row = 64B)
    const int rS = lane >> 2;                       // row within 16-row chunk
    const int gS = (lane & 3) ^ ((lane >> 3) & 3);  // swizzled source granule

    // frag-read offsets (elems); mi/ni add *512 (16 rows * 32 elems)
    const int l16 = lane & 15, quad = lane >> 4;
    const int sw = quad ^ ((l16 >> 1) & 3);
    const int aoff = (wr * 128 + l16) * 32 + sw * 8;
    const int boff = (wc * 64 + l16) * 32 + sw * 8;

    f32x4 acc[8][4];
#pragma unroll
    for (int i = 0; i < 8; i++)
#pragma unroll
        for (int j = 0; j < 4; j++)
#pragma unroll
            for (int r = 0; r < 4; r++) acc[i][j][r] = 0.f;

    auto STAGE = [&](int kt) {
        const int slot = kt & 3;
        const int kofs = kt * 32 + gS * 8;
#pragma unroll
        for (int i = 0; i < 2; i++) {
            const int r0 = wv * 32 + i * 16;
            const unsigned short* ga = Ab + (size_t)(bm + r0 + rS) * lda + kofs;
            __builtin_amdgcn_global_load_lds((gas_ptr)ga, (lds_ptr)&Asl[slot][r0 * 32], 16, 0, 0);
            const unsigned short* gb = Bb + (size_t)(bn + r0 + rS) * ldb + kofs;
            __builtin_amdgcn_global_load_lds((gas_ptr)gb, (lds_ptr)&Bsl[slot][r0 * 32], 16, 0, 0);
        }
    };

    const int nkt = Kdim / 32;
    STAGE(0); STAGE(1); STAGE(2);                   // prologue: 3 tiles in flight

    for (int kt = 0; kt < nkt; ++kt) {
        if (kt + 3 < nkt) STAGE(kt + 3);            // slot (kt-1)&3: reads done
        const int rem = nkt - 1 - kt;
        if (rem >= 3)      asm volatile("s_waitcnt vmcnt(12)" ::: "memory");
        else if (rem == 2) asm volatile("s_waitcnt vmcnt(8)" ::: "memory");
        else if (rem == 1) asm volatile("s_waitcnt vmcnt(4)" ::: "memory");
        else               asm volatile("s_waitcnt vmcnt(0)" ::: "memory");
        __builtin_amdgcn_s_barrier();               // tile kt visible to all
        asm volatile("" ::: "memory");

        const unsigned short* As = Asl[kt & 3];
        const unsigned short* Bs = Bsl[kt & 3];
        bhalf8 af[8], bf[4];
        // group A: 6 reads (bf0-3, af0-1); then pairs, order pinned by schedbar
        bf[0] = *(const bhalf8*)&Bs[boff];
        bf[1] = *(const bhalf8*)&Bs[boff + 512];
        bf[2] = *(const bhalf8*)&Bs[boff + 1024];
        bf[3] = *(const bhalf8*)&Bs[boff + 1536];
        af[0] = *(const bhalf8*)&As[aoff];
        af[1] = *(const bhalf8*)&As[aoff + 512];
        __builtin_amdgcn_sched_barrier(0);
        af[2] = *(const bhalf8*)&As[aoff + 2 * 512];
        af[3] = *(const bhalf8*)&As[aoff + 3 * 512];
        __builtin_amdgcn_sched_barrier(0);
        af[4] = *(const bhalf8*)&As[aoff + 4 * 512];
        af[5] = *(const bhalf8*)&As[aoff + 5 * 512];
        __builtin_amdgcn_sched_barrier(0);
        af[6] = *(const bhalf8*)&As[aoff + 6 * 512];
        af[7] = *(const bhalf8*)&As[aoff + 7 * 512];
        __builtin_amdgcn_sched_barrier(0);

#pragma unroll
        for (int q = 0; q < 4; q++) {
            if (q == 0)      asm volatile("s_waitcnt lgkmcnt(6)" ::: "memory");
            else if (q == 1) asm volatile("s_waitcnt lgkmcnt(4)" ::: "memory");
            else if (q == 2) asm volatile("s_waitcnt lgkmcnt(2)" ::: "memory");
            else             asm volatile("s_waitcnt lgkmcnt(0)" ::: "memory");
            __builtin_amdgcn_sched_barrier(0);
            __builtin_amdgcn_s_setprio(1);
#pragma unroll
            for (int ni = 0; ni < 4; ni++)
                acc[2 * q][ni] = __builtin_amdgcn_mfma_f32_16x16x32_bf16(
                    af[2 * q], bf[ni], acc[2 * q][ni], 0, 0, 0);
#pragma unroll
            for (int ni = 0; ni < 4; ni++)
                acc[2 * q + 1][ni] = __builtin_amdgcn_mfma_f32_16x16x32_bf16(
                    af[2 * q + 1], bf[ni], acc[2 * q + 1][ni], 0, 0, 0);
            __builtin_amdgcn_s_setprio(0);
        }
        // all my ds_reads of slot kt&3 completed (lgkmcnt(0) above);
        // closing barrier: nobody may overwrite this slot until all waves pass.
        __builtin_amdgcn_s_barrier();
        asm volatile("" ::: "memory");
    }

    // epilogue: frag D row = quad*4+r, col = l16
#pragma unroll
    for (int mi = 0; mi < 8; mi++)
#pragma unroll
        for (int ni = 0; ni < 4; ni++)
#pragma unroll
            for (int r = 0; r < 4; r++) {
                int gm = bm + wr * 128 + mi * 16 + quad * 4 + r;
                int gn = bn + wc * 64 + ni * 16 + l16;
                float v = acc[mi][ni][r];
                size_t cidx = (size_t)sC * bz + (size_t)gm * ldc + gn;
                if constexpr (MODE == 0) {
                    v = mish_f(v + bias[gn]);
                    Cp[cidx] = f2bf(v);
                } else {
                    size_t si = (size_t)bz * biasStride + gn;
                    float rr = rsqrtf(fmaxf(sumsq[si], 1e-24f));
                    v = v * rr + bias[si];
                    Cp[cidx] = f2bf(v);
                }
            }
}

// ------- bf16 NT MFMA GEMM (round-0 structure): 128 x TN tile, BK=64 -------
// Used for G3 only (N=384 not divisible by 256). Known-good at <=43.7us.
// MODE 2: C=f32 (v + bias[n] + bf2f(residbf[idx]))
template <int MODE, int SWIZ, int TN>
__global__ __launch_bounds__(256, 4) void gemm_nt(
    const unsigned short* __restrict__ A, const unsigned short* __restrict__ Bm,
    void* __restrict__ Cp, int Kdim, int lda, int ldb, int ldc,
    long sA, long sB, long sC,
    const float* __restrict__ bias, int biasStride,
    const float* __restrict__ sumsq,
    const unsigned short* __restrict__ residbf) {
    constexpr int WN = TN / 32;                    // B frags per wave (4 or 2)
    __shared__ __attribute__((aligned(16))) unsigned short Al[128 * 64];
    __shared__ __attribute__((aligned(16))) unsigned short Bl[TN * 64];

    const int tid = threadIdx.x;
    const int lane = tid & 63, wv = tid >> 6;      // 4 waves

    int bx, by, bz;
    if constexpr (SWIZ) {
        int l = blockIdx.x;
        int xcd = l & 7, s = l >> 3;
        bz = xcd * 2 + (s >> 6);
        int u = s & 63;
        bx = u & 7; by = u >> 3;
    } else {
        bx = blockIdx.x; by = blockIdx.y; bz = blockIdx.z;
    }
    const int bm = bx * 128, bn = by * TN;

    const unsigned short* Ab = A + (size_t)sA * bz;
    const unsigned short* Bb = Bm + (size_t)sB * bz;

    const int rS = lane >> 3;
    const int cS = ((lane & 7) ^ (rS & 7)) * 8;

    const int wm = (wv >> 1) * 64, wn = (wv & 1) * (TN / 2);
    const int l16 = lane & 15, quad = lane >> 4;
    const int fx = l16 & 7;

    f32x4 acc[4][WN];
#pragma unroll
    for (int i = 0; i < 4; i++)
#pragma unroll
        for (int j = 0; j < WN; j++)
#pragma unroll
            for (int r = 0; r < 4; r++) acc[i][j][r] = 0.f;

    const int ktiles = Kdim / 64;
    for (int kt = 0; kt < ktiles; ++kt) {
        const int kofs = kt * 64 + cS;
#pragma unroll
        for (int i = 0; i < 4; i++) {
            const int ch = i * 4 + wv;
            const unsigned short* ga = Ab + (size_t)(bm + ch * 8 + rS) * lda + kofs;
            __builtin_amdgcn_global_load_lds((gas_ptr)ga, (lds_ptr)&Al[ch * 512], 16, 0, 0);
        }
#pragma unroll
        for (int i = 0; i < TN / 32; i++) {
            const int ch = i * 4 + wv;
            const unsigned short* gb = Bb + (size_t)(bn + ch * 8 + rS) * ldb + kofs;
            __builtin_amdgcn_global_load_lds((gas_ptr)gb, (lds_ptr)&Bl[ch * 512], 16, 0, 0);
        }
        __syncthreads();

#pragma unroll
        for (int kk = 0; kk < 2; kk++) {
            const int cg = ((kk * 4 + quad) ^ fx) * 8;
            bhalf8 af[4], bf[WN];
#pragma unroll
            for (int mi = 0; mi < 4; mi++)
                af[mi] = *(const bhalf8*)&Al[(wm + mi * 16 + l16) * 64 + cg];
#pragma unroll
            for (int ni = 0; ni < WN; ni++)
                bf[ni] = *(const bhalf8*)&Bl[(wn + ni * 16 + l16) * 64 + cg];
#pragma unroll
            for (int mi = 0; mi < 4; mi++)
#pragma unroll
                for (int ni = 0; ni < WN; ni++)
                    acc[mi][ni] = __builtin_amdgcn_mfma_f32_16x16x32_bf16(af[mi], bf[ni],
                                                                         acc[mi][ni], 0, 0, 0);
        }
        __syncthreads();
    }

#pragma unroll
    for (int mi = 0; mi < 4; mi++)
#pragma unroll
        for (int ni = 0; ni < WN; ni++)
#pragma unroll
            for (int r = 0; r < 4; r++) {
                int gm = bm + wm + mi * 16 + quad * 4 + r;
                int gn = bn + wn + ni * 16 + l16;
                float v = acc[mi][ni][r];
                size_t cidx = (size_t)sC * bz + (size_t)gm * ldc + gn;
                if constexpr (MODE == 0) {
                    v = mish_f(v + bias[gn]);
                    ((unsigned short*)Cp)[cidx] = f2bf(v);
                } else if constexpr (MODE == 1) {
                    size_t si = (size_t)bz * biasStride + gn;
                    float rr = rsqrtf(fmaxf(sumsq[si], 1e-24f));
                    v = v * rr + bias[si];
                    ((unsigned short*)Cp)[cidx] = f2bf(v);
                } else {
                    v += bias[gn] + bf2f(residbf[cidx]);
                    ((float*)Cp)[cidx] = v;
                }
            }
}

// ---------------- launch ----------------

extern "C" void kernel_launch(void* const* d_in, const int* in_sizes, int n_in,
                              void* d_out, int out_size, void* d_ws, size_t ws_size,
                              hipStream_t stream) {
    const float* input = (const float*)d_in[0];
    const float* d_w   = (const float*)d_in[1];
    const float* d_g   = (const float*)d_in[2];
    const float* d_b   = (const float*)d_in[3];
    const float* p_w   = (const float*)d_in[4];
    const float* p_g   = (const float*)d_in[5];
    const float* p_b   = (const float*)d_in[6];
    const float* w1_w  = (const float*)d_in[7];
    const float* w1_b  = (const float*)d_in[8];
    const float* w2_w  = (const float*)d_in[9];
    const float* w2_b  = (const float*)d_in[10];
    float* out = (float*)d_out;

    char* ws = (char*)d_ws;
    size_t off = 0;
    auto alloc = [&](size_t bytes) {
        char* p = ws + off;
        off += (bytes + 255) & ~(size_t)255;
        return p;
    };
    float* dwn_s         = (float*)alloc((size_t)BCNT * H1 * KW * 4);
    float* sumsq         = (float*)alloc((size_t)BCNT * H2 * 4);
    unsigned short* inbf = (unsigned short*)alloc((size_t)BCNT * TT * DIN * 2);
    unsigned short* w1bf = (unsigned short*)alloc((size_t)H1 * DIN * 2);
    unsigned short* w2bf = (unsigned short*)alloc((size_t)DIN * H2 * 2);
    unsigned short* h    = (unsigned short*)alloc((size_t)BCNT * TT * H1 * 2);
    unsigned short* y    = (unsigned short*)alloc((size_t)BCNT * TT * H1 * 2);
    unsigned short* pwTu = (unsigned short*)alloc((size_t)BCNT * H2 * H1 * 2);
    unsigned short* zt   = (unsigned short*)alloc((size_t)BCNT * TT * H2 * 2);

    // f32 -> bf16 conversions + zero sumsq (one launch)
    const int n4_in = BCNT * TT * DIN / 4, n4_w1 = H1 * DIN / 4, n4_w2 = DIN * H2 / 4;
    const int n4_z = BCNT * H2 / 4;
    k_cvt3z<<<(n4_in + n4_w1 + n4_w2 + n4_z + 255) / 256, 256, 0, stream>>>(
        input, inbf, n4_in, w1_w, w1bf, n4_w1, w2_w, w2bf, n4_w2, sumsq, n4_z);

    // weight prep
    k_norm_dwn<<<BCNT * KW, 256, 0, stream>>>(d_w, d_g, dwn_s);
    k_tpw2<<<dim3(H1 / 32, H2 / 32, BCNT), 256, 0, stream>>>(p_w, p_g, pwTu, sumsq);

    // G1: h = bf16(mish(input @ w1_w^T + w1_b)); 64 M-tiles x 4 N = 256 blocks
    gemm256<0, 0><<<256, 512, 0, stream>>>(
        inbf, w1bf, h, DIN, DIN, DIN, H1, 0, 0, 0, w1_b, 0, nullptr);

    // depthwise conv -> y (B*T, H1) bf16
    k_conv<<<dim3(TT / 64, H1 / 512, BCNT), 256, 0, stream>>>(h, dwn_s, d_b, y);

    // G2 (batched): zt = rsqrt(sumsq)*(y.pwTu) + p_b; 16 tiles x 16 batches
    gemm256<1, 1><<<256, 512, 0, stream>>>(
        y, pwTu, zt, H1, H1, H1, H2, (long)TT * H1, (long)H2 * H1, (long)TT * H2,
        p_b, H2, sumsq);

    // G3: out = zt @ w2^T + w2_b + resid; 128x64 tiles -> 768 blocks (round-0)
    gemm_nt<2, 0, 64><<<dim3(BCNT * TT / 128, DIN / 64, 1), 256, 0, stream>>>(
        zt, w2bf, out, H2, H2, H2, DIN, 0, 0, 0, w2_b, 0, nullptr, inbf);
}

// Round 4
// 260.834 us; speedup vs baseline: 1.0925x; 1.0925x over previous
//
#include <hip/hip_runtime.h>

#define BCNT 16
#define TT 1024
#define DIN 384
#define H1 1024
#define H2 1024
#define KW 9

typedef __attribute__((ext_vector_type(8))) short bhalf8;   // 8 bf16 in 4 VGPRs
typedef __attribute__((ext_vector_type(4))) float f32x4;

typedef const __attribute__((address_space(1))) void* gas_ptr;
typedef __attribute__((address_space(3))) void* lds_ptr;

__device__ __forceinline__ float bf2f(unsigned short u) {
    return __uint_as_float(((unsigned int)u) << 16);
}
__device__ __forceinline__ unsigned short f2bf(float f) {
    unsigned int u = __float_as_uint(f);
    unsigned int r = (u + 0x7FFFu + ((u >> 16) & 1u)) >> 16;  // RNE
    return (unsigned short)r;
}
// mish(x) = x*tanh(log1p(e^x)) = x*(u^2+2u)/(u^2+2u+2), u=e^x (exact algebra)
__device__ __forceinline__ float mish_f(float x) {
    if (x > 20.f) return x;
    float u = __expf(x);
    float n = u * u + 2.f * u;
    return x * n / (n + 2.f);
}

// ---------------- prep kernels ----------------

// fused f32->bf16 cvt for input, w1_w, w2_w + zero sumsq (one launch)
__global__ __launch_bounds__(256) void k_cvt3z(
    const float* __restrict__ s0, unsigned short* __restrict__ d0, int n0,
    const float* __restrict__ s1, unsigned short* __restrict__ d1, int n1,
    const float* __restrict__ s2, unsigned short* __restrict__ d2, int n2,
    float* __restrict__ zb, int n3) {
    int i = blockIdx.x * 256 + threadIdx.x;
    const float* s; unsigned short* d; int j = i;
    if (i < n0) { s = s0; d = d0; }
    else if ((j = i - n0) < n1) { s = s1; d = d1; }
    else if ((j = i - n0 - n1) < n2) { s = s2; d = d2; }
    else if ((j = i - n0 - n1 - n2) < n3) {
        ((float4*)zb)[j] = make_float4(0.f, 0.f, 0.f, 0.f);
        return;
    } else return;
    float4 v = ((const float4*)s)[j];
    ushort4 o;
    o.x = f2bf(v.x); o.y = f2bf(v.y); o.z = f2bf(v.z); o.w = f2bf(v.w);
    ((ushort4*)d)[j] = o;
}

// per-(b,k): norm of d_w over c, then write dwn_s[b,c,k] = d_w/n * d_g * T
__global__ void k_norm_dwn(const float* __restrict__ d_w, const float* __restrict__ d_g,
                           float* __restrict__ dwn_s) {
    int idx = blockIdx.x;           // b*KW + k
    int b = idx / KW, k = idx % KW;
    float s = 0.f;
    for (int c = threadIdx.x; c < H1; c += 256) {
        float v = d_w[((size_t)b * H1 + c) * KW + k];
        s += v * v;
    }
    __shared__ float red[256];
    __shared__ float nsh;
    red[threadIdx.x] = s; __syncthreads();
    for (int st = 128; st > 0; st >>= 1) {
        if (threadIdx.x < st) red[threadIdx.x] += red[threadIdx.x + st];
        __syncthreads();
    }
    if (threadIdx.x == 0) nsh = fmaxf(sqrtf(red[0]), 1e-12f);
    __syncthreads();
    float n = nsh;
    for (int c = threadIdx.x; c < H1; c += 256) {
        size_t o = ((size_t)b * H1 + c) * KW + k;
        dwn_s[o] = d_w[o] / n * d_g[b * H1 + c] * (float)TT;
    }
}

// transpose+scale p_w AND per-(b,o) sumsq. Vectorized: 32c x 128o tile,
// float4 (16B/lane) reads, 2x bhalf8 (32B/thread) transposed writes.
// grid (H1/32, H2/128, B) = (32, 8, 16) = 4096 blocks.
__global__ __launch_bounds__(256) void k_tpw3(const float* __restrict__ p_w,
                                              const float* __restrict__ p_g,
                                              unsigned short* __restrict__ pwTu,
                                              float* __restrict__ sumsq) {
    __shared__ float tile[32][132];      // 132*4=528B rows: 16B-aligned, pad kills
    __shared__ float sred[8][32][4];     //  phase-2 column-read conflicts (2-way max)
    __shared__ float pg[32];
    const int tid = threadIdx.x;
    const int tx = tid & 31, ty = tid >> 5;         // 32 x 8
    const int c0 = blockIdx.x * 32, o0 = blockIdx.y * 128, b = blockIdx.z;
    if (tid < 32) pg[tid] = p_g[(size_t)b * H1 + c0 + tid];
    const float4* pw4 = (const float4*)p_w;
    float s0 = 0.f, s1 = 0.f, s2 = 0.f, s3 = 0.f;
#pragma unroll
    for (int j = 0; j < 4; j++) {
        int cl = ty + j * 8;
        float4 v = pw4[(size_t)(b * H1 + c0 + cl) * (H2 / 4) + (o0 / 4) + tx];
        *(float4*)&tile[cl][tx * 4] = v;
        s0 += v.x * v.x; s1 += v.y * v.y; s2 += v.z * v.z; s3 += v.w * v.w;
    }
    sred[ty][tx][0] = s0; sred[ty][tx][1] = s1;
    sred[ty][tx][2] = s2; sred[ty][tx][3] = s3;
    __syncthreads();
    if (tid < 128) {
        int txo = tid >> 2, q = tid & 3;
        float t = 0.f;
#pragma unroll
        for (int r = 0; r < 8; r++) t += sred[r][txo][q];
        atomicAdd(&sumsq[(size_t)b * H2 + o0 + txo * 4 + q], t);
    }
    // transpose write: thread pair (2k,2k+1) covers o-row k, c halves 0/16
    const int ol = tid >> 1, half = (tid & 1) * 16;
    unsigned short outv[16];
#pragma unroll
    for (int i = 0; i < 16; i++)
        outv[i] = f2bf(tile[half + i][ol] * pg[half + i]);
    unsigned short* dst = &pwTu[((size_t)b * H2 + o0 + ol) * H1 + c0 + half];
    *(bhalf8*)dst = *(const bhalf8*)&outv[0];
    *(bhalf8*)&dst[8] = *(const bhalf8*)&outv[8];
}

// depthwise conv along T. Vectorized: 4 channels/thread (ushort4, 8B/lane),
// t-block 16 -> grid (64,1,16) = 1024 blocks = 4 blk/CU (16 waves/CU TLP).
// Fully unrolled sliding window (copy-prop removes shifts).
__global__ __launch_bounds__(256) void k_conv4(const unsigned short* __restrict__ h,
                                               const float* __restrict__ dwn_s,
                                               const float* __restrict__ d_b,
                                               unsigned short* __restrict__ y) {
    const int tid = threadIdx.x;
    const int c = tid * 4;                 // 256 threads cover H1=1024
    const int t0 = blockIdx.x * 16;
    const int b = blockIdx.z;
    const ushort4* hb = (const ushort4*)(h + (size_t)b * TT * H1);
    ushort4* yb = (ushort4*)(y + (size_t)b * TT * H1);
    float kk[KW][4], db[4];
#pragma unroll
    for (int q = 0; q < 4; q++) {
        db[q] = d_b[b * H1 + c + q];
#pragma unroll
        for (int i = 0; i < KW; i++)
            kk[i][q] = dwn_s[((size_t)b * H1 + c + q) * KW + i];
    }
    float w[KW][4];
#pragma unroll
    for (int i = 0; i < 8; i++) {
        int t = t0 - 4 + i;
        if (t >= 0) {                      // t < TT always here
            ushort4 v = hb[(size_t)t * (H1 / 4) + tid];
            w[i][0] = bf2f(v.x); w[i][1] = bf2f(v.y);
            w[i][2] = bf2f(v.z); w[i][3] = bf2f(v.w);
        } else { w[i][0] = w[i][1] = w[i][2] = w[i][3] = 0.f; }
    }
#pragma unroll
    for (int j = 0; j < 16; j++) {
        const int t = t0 + j, tl = t + 4;
        if (tl < TT) {
            ushort4 v = hb[(size_t)tl * (H1 / 4) + tid];
            w[8][0] = bf2f(v.x); w[8][1] = bf2f(v.y);
            w[8][2] = bf2f(v.z); w[8][3] = bf2f(v.w);
        } else { w[8][0] = w[8][1] = w[8][2] = w[8][3] = 0.f; }
        float a0 = db[0], a1 = db[1], a2 = db[2], a3 = db[3];
#pragma unroll
        for (int i = 0; i < KW; i++) {
            a0 += kk[i][0] * w[i][0]; a1 += kk[i][1] * w[i][1];
            a2 += kk[i][2] * w[i][2]; a3 += kk[i][3] * w[i][3];
        }
        ushort4 o;
        o.x = f2bf(a0); o.y = f2bf(a1); o.z = f2bf(a2); o.w = f2bf(a3);
        yb[(size_t)t * (H1 / 4) + tid] = o;
#pragma unroll
        for (int i = 0; i < 8; i++) {
            w[i][0] = w[i + 1][0]; w[i][1] = w[i + 1][1];
            w[i][2] = w[i + 1][2]; w[i][3] = w[i + 1][3];
        }
    }
}

// ------- bf16 NT MFMA GEMM (round-0 structure, best measured): 128 x TN tile -------
// C[m,n] = sum_k A[m,k]*B[n,k], bf16 K-contiguous. BK=64. 4 blocks/CU.
// LDS rows 64 bf16 = 128 B. Staging chunk = 8 rows (64 lanes x 16 B); lane covers
// (row=lane>>3, slot=lane&7); slot holds global col-group slot^(row&7) [XOR swizzle,
// conflict-free on ds_read_b128]. TN=128: 4 waves as 2x2, wave=64x64, acc 4x4.
// TN=64: wave=64x32, acc 4x2.
// MODE 0: C=bf16(mish(v + bias[n]))
// MODE 1: C=bf16(v*rsqrt(sumsq[bz*str+n]) + bias[bz*str+n])
// MODE 2: C=f32 (v + bias[n] + bf2f(residbf[idx]))
template <int MODE, int SWIZ, int TN>
__global__ __launch_bounds__(256, 4) void gemm_nt(
    const unsigned short* __restrict__ A, const unsigned short* __restrict__ Bm,
    void* __restrict__ Cp, int Kdim, int lda, int ldb, int ldc,
    long sA, long sB, long sC,
    const float* __restrict__ bias, int biasStride,
    const float* __restrict__ sumsq,
    const unsigned short* __restrict__ residbf) {
    constexpr int WN = TN / 32;                    // B frags per wave (4 or 2)
    __shared__ __attribute__((aligned(16))) unsigned short Al[128 * 64];
    __shared__ __attribute__((aligned(16))) unsigned short Bl[TN * 64];

    const int tid = threadIdx.x;
    const int lane = tid & 63, wv = tid >> 6;      // 4 waves

    int bx, by, bz;
    if constexpr (SWIZ) {
        // G2: 1024 blocks. XCD k owns batches {2k,2k+1}; m-tile fastest.
        int l = blockIdx.x;
        int xcd = l & 7, s = l >> 3;               // s: 0..127
        bz = xcd * 2 + (s >> 6);
        int u = s & 63;
        bx = u & 7; by = u >> 3;
    } else {
        bx = blockIdx.x; by = blockIdx.y; bz = blockIdx.z;
    }
    const int bm = bx * 128, bn = by * TN;

    const unsigned short* Ab = A + (size_t)sA * bz;
    const unsigned short* Bb = Bm + (size_t)sB * bz;

    // staging lane map (XOR swizzle on source column)
    const int rS = lane >> 3;                       // row within 8-row chunk
    const int cS = ((lane & 7) ^ (rS & 7)) * 8;     // global col-group offset (elems)

    const int wm = (wv >> 1) * 64, wn = (wv & 1) * (TN / 2);
    const int l16 = lane & 15, quad = lane >> 4;
    const int fx = l16 & 7;                         // read-side XOR key

    f32x4 acc[4][WN];
#pragma unroll
    for (int i = 0; i < 4; i++)
#pragma unroll
        for (int j = 0; j < WN; j++)
#pragma unroll
            for (int r = 0; r < 4; r++) acc[i][j][r] = 0.f;

    const int ktiles = Kdim / 64;
    for (int kt = 0; kt < ktiles; ++kt) {
        const int kofs = kt * 64 + cS;
        // A: 16 chunks of 8 rows, 4 per wave
#pragma unroll
        for (int i = 0; i < 4; i++) {
            const int ch = i * 4 + wv;
            const unsigned short* ga = Ab + (size_t)(bm + ch * 8 + rS) * lda + kofs;
            __builtin_amdgcn_global_load_lds((gas_ptr)ga, (lds_ptr)&Al[ch * 512], 16, 0, 0);
        }
        // B: TN/8 chunks, TN/32 per wave
#pragma unroll
        for (int i = 0; i < TN / 32; i++) {
            const int ch = i * 4 + wv;
            const unsigned short* gb = Bb + (size_t)(bn + ch * 8 + rS) * ldb + kofs;
            __builtin_amdgcn_global_load_lds((gas_ptr)gb, (lds_ptr)&Bl[ch * 512], 16, 0, 0);
        }
        __syncthreads();

#pragma unroll
        for (int kk = 0; kk < 2; kk++) {
            const int cg = ((kk * 4 + quad) ^ fx) * 8;   // swizzled col offset
            bhalf8 af[4], bf[WN];
#pragma unroll
            for (int mi = 0; mi < 4; mi++)
                af[mi] = *(const bhalf8*)&Al[(wm + mi * 16 + l16) * 64 + cg];
#pragma unroll
            for (int ni = 0; ni < WN; ni++)
                bf[ni] = *(const bhalf8*)&Bl[(wn + ni * 16 + l16) * 64 + cg];
#pragma unroll
            for (int mi = 0; mi < 4; mi++)
#pragma unroll
                for (int ni = 0; ni < WN; ni++)
                    acc[mi][ni] = __builtin_amdgcn_mfma_f32_16x16x32_bf16(af[mi], bf[ni],
                                                                         acc[mi][ni], 0, 0, 0);
        }
        __syncthreads();
    }

    // epilogue: D row = quad*4+r, col = lane&15
#pragma unroll
    for (int mi = 0; mi < 4; mi++)
#pragma unroll
        for (int ni = 0; ni < WN; ni++)
#pragma unroll
            for (int r = 0; r < 4; r++) {
                int gm = bm + wm + mi * 16 + quad * 4 + r;
                int gn = bn + wn + ni * 16 + l16;
                float v = acc[mi][ni][r];
                size_t cidx = (size_t)sC * bz + (size_t)gm * ldc + gn;
                if constexpr (MODE == 0) {
                    v = mish_f(v + bias[gn]);
                    ((unsigned short*)Cp)[cidx] = f2bf(v);
                } else if constexpr (MODE == 1) {
                    size_t si = (size_t)bz * biasStride + gn;
                    float rr = rsqrtf(fmaxf(sumsq[si], 1e-24f));
                    v = v * rr + bias[si];
                    ((unsigned short*)Cp)[cidx] = f2bf(v);
                } else {
                    v += bias[gn] + bf2f(residbf[cidx]);
                    ((float*)Cp)[cidx] = v;
                }
            }
}

// ---------------- launch ----------------

extern "C" void kernel_launch(void* const* d_in, const int* in_sizes, int n_in,
                              void* d_out, int out_size, void* d_ws, size_t ws_size,
                              hipStream_t stream) {
    const float* input = (const float*)d_in[0];
    const float* d_w   = (const float*)d_in[1];
    const float* d_g   = (const float*)d_in[2];
    const float* d_b   = (const float*)d_in[3];
    const float* p_w   = (const float*)d_in[4];
    const float* p_g   = (const float*)d_in[5];
    const float* p_b   = (const float*)d_in[6];
    const float* w1_w  = (const float*)d_in[7];
    const float* w1_b  = (const float*)d_in[8];
    const float* w2_w  = (const float*)d_in[9];
    const float* w2_b  = (const float*)d_in[10];
    float* out = (float*)d_out;

    char* ws = (char*)d_ws;
    size_t off = 0;
    auto alloc = [&](size_t bytes) {
        char* p = ws + off;
        off += (bytes + 255) & ~(size_t)255;
        return p;
    };
    float* dwn_s         = (float*)alloc((size_t)BCNT * H1 * KW * 4);
    float* sumsq         = (float*)alloc((size_t)BCNT * H2 * 4);
    unsigned short* inbf = (unsigned short*)alloc((size_t)BCNT * TT * DIN * 2);
    unsigned short* w1bf = (unsigned short*)alloc((size_t)H1 * DIN * 2);
    unsigned short* w2bf = (unsigned short*)alloc((size_t)DIN * H2 * 2);
    unsigned short* h    = (unsigned short*)alloc((size_t)BCNT * TT * H1 * 2);
    unsigned short* y    = (unsigned short*)alloc((size_t)BCNT * TT * H1 * 2);
    unsigned short* pwTu = (unsigned short*)alloc((size_t)BCNT * H2 * H1 * 2);
    unsigned short* zt   = (unsigned short*)alloc((size_t)BCNT * TT * H2 * 2);

    // f32 -> bf16 conversions + zero sumsq (one launch)
    const int n4_in = BCNT * TT * DIN / 4, n4_w1 = H1 * DIN / 4, n4_w2 = DIN * H2 / 4;
    const int n4_z = BCNT * H2 / 4;
    k_cvt3z<<<(n4_in + n4_w1 + n4_w2 + n4_z + 255) / 256, 256, 0, stream>>>(
        input, inbf, n4_in, w1_w, w1bf, n4_w1, w2_w, w2bf, n4_w2, sumsq, n4_z);

    // weight prep
    k_norm_dwn<<<BCNT * KW, 256, 0, stream>>>(d_w, d_g, dwn_s);
    k_tpw3<<<dim3(H1 / 32, H2 / 128, BCNT), 256, 0, stream>>>(p_w, p_g, pwTu, sumsq);

    // G1: h = bf16(mish(input @ w1_w^T + w1_b)), (B*T, H1); 1024 blocks, 6 K-iters
    gemm_nt<0, 0, 128><<<dim3(BCNT * TT / 128, H1 / 128, 1), 256, 0, stream>>>(
        inbf, w1bf, h, DIN, DIN, DIN, H1, 0, 0, 0, w1_b, 0, nullptr, nullptr);

    // depthwise conv -> y (B*T, H1) bf16; 1024 blocks, 4ch/thread
    k_conv4<<<dim3(TT / 16, 1, BCNT), 256, 0, stream>>>(h, dwn_s, d_b, y);

    // G2 (batched, XCD-swizzled, 1024 blocks): zt = rsqrt(sumsq)*(y.pwTu) + p_b
    gemm_nt<1, 1, 128><<<dim3(1024, 1, 1), 256, 0, stream>>>(
        y, pwTu, zt, H1, H1, H1, H2, (long)TT * H1, (long)H2 * H1, (long)TT * H2,
        p_b, H2, sumsq, nullptr);

    // G3: out = zt @ w2^T + w2_b + resid; 128x64 tiles -> 768 blocks
    gemm_nt<2, 0, 64><<<dim3(BCNT * TT / 128, DIN / 64, 1), 256, 0, stream>>>(
        zt, w2bf, out, H2, H2, H2, DIN, 0, 0, 0, w2_b, 0, nullptr, inbf);
}